// Round 11
// baseline (212.877 us; speedup 1.0000x reference)
//
#include <hip/hip_runtime.h>
#include <math.h>

typedef __attribute__((ext_vector_type(8))) short bf16x8;
typedef __attribute__((ext_vector_type(4))) float f32x4;

constexpr int kN   = 50000;
constexpr int kR   = 8;
constexpr int kIn  = 128;
constexpr int kHid = 128;
constexpr int kOut = 40;
constexpr int kNT  = 16;              // dst nodes per block (old path)
constexpr int kLds = 1032;            // old-path ushort row stride
constexpr float kBnEps = 1e-5f;

// bf16 RNE (prep only)
__device__ inline ushort f2bf(float x) {
    uint u = __float_as_uint(x);
    u += 0x7FFFu + ((u >> 16) & 1u);
    return (ushort)(u >> 16);
}
__device__ inline float bf2f(ushort s) { return __uint_as_float(((uint)s) << 16); }
// cheap half-up pack (accepted error class since R7)
__device__ inline ushort f2bf_c(float x) {
    return (ushort)((__float_as_uint(x) + 0x8000u) >> 16);
}

// ===========================================================================
// ======================  NEW PATH (xform + gather-sum)  ====================
// ===========================================================================

// ---------------------------------------------------------------------------
// prep_new: blocks 0..3124  : cast x fp32->bf16 (8 elems/thread)
//           blocks 3125..3188: pack W1' -> B-frags, cols n = r*128+h (N=1024)
//           blocks 3189..3220: pack W2' -> B-frags, cols n = r*64+h  (N=512,
//                              h>=40 zero-padded)
// Frag f = nt*4 + kt; lane L holds B[n=nt*16+(L&15)][k=kt*32+(L>>4)*8+j].
// ---------------------------------------------------------------------------
__global__ __launch_bounds__(256)
void prep_new(const float* __restrict__ x,  ushort* __restrict__ xb,
              const float* __restrict__ W1, ushort* __restrict__ W1p,
              const float* __restrict__ W2, ushort* __restrict__ W2p)
{
    const int b   = blockIdx.x;
    const int tid = threadIdx.x;
    if (b < 3125) {
        const size_t i = ((size_t)b * 256 + tid) * 8;
        const float4 v0 = *(const float4*)&x[i];
        const float4 v1 = *(const float4*)&x[i + 4];
        *(ushort4*)&xb[i]     = make_ushort4(f2bf(v0.x), f2bf(v0.y), f2bf(v0.z), f2bf(v0.w));
        *(ushort4*)&xb[i + 4] = make_ushort4(f2bf(v1.x), f2bf(v1.y), f2bf(v1.z), f2bf(v1.w));
        return;
    }
    const int lane = tid & 63;
    const int m = lane & 15, q = lane >> 4;
    ushort hv[8];
    if (b < 3125 + 64) {                        // W1': 256 frags
        const int f  = (b - 3125) * 4 + (tid >> 6);
        const int nt = f >> 2, kt = f & 3;
        const int n  = nt * 16 + m;             // n = r*128 + h
        const int r  = n >> 7, h = n & 127;
        #pragma unroll
        for (int j = 0; j < 8; ++j) {
            const int k = kt * 32 + q * 8 + j;  // k = input dim d
            hv[j] = f2bf(W1[(size_t)r * 16384 + (size_t)k * 128 + h]);
        }
        const size_t o = ((size_t)f * 64 + lane) * 8;
        *(ushort4*)&W1p[o]     = make_ushort4(hv[0], hv[1], hv[2], hv[3]);
        *(ushort4*)&W1p[o + 4] = make_ushort4(hv[4], hv[5], hv[6], hv[7]);
    } else {                                    // W2': 128 frags
        const int f  = (b - 3189) * 4 + (tid >> 6);
        const int nt = f >> 2, kt = f & 3;
        const int n  = nt * 16 + m;             // n = r*64 + h (pad h>=40)
        const int r  = n >> 6, h = n & 63;
        #pragma unroll
        for (int j = 0; j < 8; ++j) {
            const int k = kt * 32 + q * 8 + j;
            hv[j] = (h < kOut) ? f2bf(W2[(size_t)r * 5120 + (size_t)k * 40 + h])
                               : (ushort)0;
        }
        const size_t o = ((size_t)f * 64 + lane) * 8;
        *(ushort4*)&W2p[o]     = make_ushort4(hv[0], hv[1], hv[2], hv[3]);
        *(ushort4*)&W2p[o + 4] = make_ushort4(hv[4], hv[5], hv[6], hv[7]);
    }
}

// ---------------------------------------------------------------------------
// xform<NTW,NCOLS>: out[row][col] = in[row][:128] @ B'  (dense bf16 GEMM)
// 64-row M-tile per block; A staged in LDS then preloaded to 16 reg frags;
// wave w covers n-tiles w*NTW .. w*NTW+NTW-1 (4 m-tiles each).
// ---------------------------------------------------------------------------
#define LOADA(MT,KT) const bf16x8 af##MT##KT = \
    *(const bf16x8*)&As[MT * 16 + m][KT * 32 + q * 8];

template<int NTW, int NCOLS>
__global__ __launch_bounds__(512, 4)
void xform(const ushort* __restrict__ in,     // [kN][128] bf16
           const ushort* __restrict__ Bp,     // B-frags
           ushort* __restrict__ outp)         // [kN][NCOLS] bf16
{
    __shared__ ushort As[64][136];             // +8 pad: 16B-aligned, bank-safe
    const int tid  = threadIdx.x;
    const int base = blockIdx.x * 64;

    {   // stage A: 64 rows x 128 bf16; thread -> chunks c, c+8 of its row
        const int row = tid >> 3, c = tid & 7;
        const int gr  = base + row;
        bf16x8 v0 = {0,0,0,0,0,0,0,0}, v1 = {0,0,0,0,0,0,0,0};
        if (gr < kN) {
            v0 = *(const bf16x8*)&in[(size_t)gr * 128 + c * 8];
            v1 = *(const bf16x8*)&in[(size_t)gr * 128 + c * 8 + 64];
        }
        *(bf16x8*)&As[row][c * 8]      = v0;
        *(bf16x8*)&As[row][c * 8 + 64] = v1;
    }
    __syncthreads();

    const int lane = tid & 63, wid = tid >> 6;
    const int m = lane & 15, q = lane >> 4;

    LOADA(0,0) LOADA(0,1) LOADA(0,2) LOADA(0,3)
    LOADA(1,0) LOADA(1,1) LOADA(1,2) LOADA(1,3)
    LOADA(2,0) LOADA(2,1) LOADA(2,2) LOADA(2,3)
    LOADA(3,0) LOADA(3,1) LOADA(3,2) LOADA(3,3)

    const bf16x8* B8 = (const bf16x8*)Bp;

    #pragma unroll
    for (int ii = 0; ii < NTW; ++ii) {
        const int nt = wid * NTW + ii;
        const bf16x8 b0 = B8[(size_t)(nt * 4 + 0) * 64 + lane];
        const bf16x8 b1 = B8[(size_t)(nt * 4 + 1) * 64 + lane];
        const bf16x8 b2 = B8[(size_t)(nt * 4 + 2) * 64 + lane];
        const bf16x8 b3 = B8[(size_t)(nt * 4 + 3) * 64 + lane];
        f32x4 c0 = {0.f,0.f,0.f,0.f}, c1 = {0.f,0.f,0.f,0.f};
        f32x4 c2 = {0.f,0.f,0.f,0.f}, c3 = {0.f,0.f,0.f,0.f};
        c0 = __builtin_amdgcn_mfma_f32_16x16x32_bf16(af00, b0, c0, 0, 0, 0);
        c1 = __builtin_amdgcn_mfma_f32_16x16x32_bf16(af10, b0, c1, 0, 0, 0);
        c2 = __builtin_amdgcn_mfma_f32_16x16x32_bf16(af20, b0, c2, 0, 0, 0);
        c3 = __builtin_amdgcn_mfma_f32_16x16x32_bf16(af30, b0, c3, 0, 0, 0);
        c0 = __builtin_amdgcn_mfma_f32_16x16x32_bf16(af01, b1, c0, 0, 0, 0);
        c1 = __builtin_amdgcn_mfma_f32_16x16x32_bf16(af11, b1, c1, 0, 0, 0);
        c2 = __builtin_amdgcn_mfma_f32_16x16x32_bf16(af21, b1, c2, 0, 0, 0);
        c3 = __builtin_amdgcn_mfma_f32_16x16x32_bf16(af31, b1, c3, 0, 0, 0);
        c0 = __builtin_amdgcn_mfma_f32_16x16x32_bf16(af02, b2, c0, 0, 0, 0);
        c1 = __builtin_amdgcn_mfma_f32_16x16x32_bf16(af12, b2, c1, 0, 0, 0);
        c2 = __builtin_amdgcn_mfma_f32_16x16x32_bf16(af22, b2, c2, 0, 0, 0);
        c3 = __builtin_amdgcn_mfma_f32_16x16x32_bf16(af32, b2, c3, 0, 0, 0);
        c0 = __builtin_amdgcn_mfma_f32_16x16x32_bf16(af03, b3, c0, 0, 0, 0);
        c1 = __builtin_amdgcn_mfma_f32_16x16x32_bf16(af13, b3, c1, 0, 0, 0);
        c2 = __builtin_amdgcn_mfma_f32_16x16x32_bf16(af23, b3, c2, 0, 0, 0);
        c3 = __builtin_amdgcn_mfma_f32_16x16x32_bf16(af33, b3, c3, 0, 0, 0);

        const int col = nt * 16 + m;
        #define STORE_MT(CC, MT) {                                          \
            const int r0 = base + MT * 16 + q * 4;                          \
            _Pragma("unroll")                                               \
            for (int i2 = 0; i2 < 4; ++i2) {                                \
                const int rr = r0 + i2;                                     \
                if (rr < kN)                                                \
                    outp[(size_t)rr * NCOLS + col] = f2bf_c(CC[i2]);        \
            } }
        STORE_MT(c0, 0) STORE_MT(c1, 1) STORE_MT(c2, 2) STORE_MT(c3, 3)
        #undef STORE_MT
    }
}

// ---------------------------------------------------------------------------
// agg_bn: h1[n][c] = relu(bn( (sum_e xr1[(src_e*8+et_e)]) / deg ))
// One wave per node; lane owns channel pair 2L, 2L+1 (one dword of the
// 256 B relation-slice). No LDS, no barrier, no branches per edge.
// ---------------------------------------------------------------------------
#define GADD(BV, GJ) \
    const uint BV = xrU[(size_t)(GJ) * 64 + lane]; \
    ax += __uint_as_float((BV) << 16); \
    ay += __uint_as_float((BV) & 0xffff0000u);

__global__ __launch_bounds__(512, 4)
void agg_bn(const ushort* __restrict__ xr1,
            const int* __restrict__ ptr, const int* __restrict__ idx,
            const int* __restrict__ etype,
            const float* __restrict__ gamma, const float* __restrict__ beta,
            const float* __restrict__ mean,  const float* __restrict__ var,
            ushort* __restrict__ h1b)
{
    const int lane = threadIdx.x & 63;
    const int wid  = threadIdx.x >> 6;
    const int node = blockIdx.x * 8 + wid;
    const int p0 = ptr[node], p1 = ptr[node + 1];
    const int deg = p1 - p0;
    const uint* xrU = (const uint*)xr1;

    float ax = 0.f, ay = 0.f;
    if (deg == 16) {
        const int gv = (idx[p0 + (lane & 15)] << 3) | etype[p0 + (lane & 15)];
        const int g0  = __builtin_amdgcn_readlane(gv, 0);
        const int g1  = __builtin_amdgcn_readlane(gv, 1);
        const int g2  = __builtin_amdgcn_readlane(gv, 2);
        const int g3  = __builtin_amdgcn_readlane(gv, 3);
        const int g4  = __builtin_amdgcn_readlane(gv, 4);
        const int g5  = __builtin_amdgcn_readlane(gv, 5);
        const int g6  = __builtin_amdgcn_readlane(gv, 6);
        const int g7  = __builtin_amdgcn_readlane(gv, 7);
        const int g8  = __builtin_amdgcn_readlane(gv, 8);
        const int g9  = __builtin_amdgcn_readlane(gv, 9);
        const int g10 = __builtin_amdgcn_readlane(gv, 10);
        const int g11 = __builtin_amdgcn_readlane(gv, 11);
        const int g12 = __builtin_amdgcn_readlane(gv, 12);
        const int g13 = __builtin_amdgcn_readlane(gv, 13);
        const int g14 = __builtin_amdgcn_readlane(gv, 14);
        const int g15 = __builtin_amdgcn_readlane(gv, 15);
        GADD(b0,  g0)  GADD(b1,  g1)  GADD(b2,  g2)  GADD(b3,  g3)
        GADD(b4,  g4)  GADD(b5,  g5)  GADD(b6,  g6)  GADD(b7,  g7)
        GADD(b8,  g8)  GADD(b9,  g9)  GADD(b10, g10) GADD(b11, g11)
        GADD(b12, g12) GADD(b13, g13) GADD(b14, g14) GADD(b15, g15)
    } else {                                   // generic fallback (never hit)
        for (int e = p0; e < p1; ++e) {
            const int src = __builtin_amdgcn_readfirstlane(idx[e]);
            const int et  = __builtin_amdgcn_readfirstlane(etype[e]);
            const uint b  = xrU[((size_t)src * 8 + et) * 64 + lane];
            ax += __uint_as_float(b << 16);
            ay += __uint_as_float(b & 0xffff0000u);
        }
    }

    const float invd = 1.0f / (float)deg;
    const int c0 = lane * 2;
    const float2 gm = *(const float2*)&gamma[c0];
    const float2 bt = *(const float2*)&beta[c0];
    const float2 mu = *(const float2*)&mean[c0];
    const float2 vr = *(const float2*)&var[c0];
    float v0 = (ax * invd - mu.x) * (gm.x * rsqrtf(vr.x + kBnEps)) + bt.x;
    float v1 = (ay * invd - mu.y) * (gm.y * rsqrtf(vr.y + kBnEps)) + bt.y;
    v0 = fmaxf(v0, 0.f);
    v1 = fmaxf(v1, 0.f);
    const uint px = (__float_as_uint(v0) + 0x8000u) >> 16;
    const uint py = (__float_as_uint(v1) + 0x8000u) & 0xffff0000u;
    ((uint*)h1b)[(size_t)node * 64 + lane] = px | py;
}

// ---------------------------------------------------------------------------
// agg_sm: out[n][:40] = log_softmax( (sum_e xr2[src_e*8+et_e]) / deg )
// One wave per node; lanes 0..19 own logit pairs 2L, 2L+1 (40 cols of the
// 64-padded relation slice). Gather under lane<20 mask -> 80 B/edge.
// ---------------------------------------------------------------------------
#define GADD2(BV, GJ) \
    const uint BV = xrU[(size_t)(GJ) * 32 + lane]; \
    ax += __uint_as_float((BV) << 16); \
    ay += __uint_as_float((BV) & 0xffff0000u);

__global__ __launch_bounds__(512, 4)
void agg_sm(const ushort* __restrict__ xr2,
            const int* __restrict__ ptr, const int* __restrict__ idx,
            const int* __restrict__ etype,
            float* __restrict__ out)
{
    const int lane = threadIdx.x & 63;
    const int wid  = threadIdx.x >> 6;
    const int node = blockIdx.x * 8 + wid;
    const int p0 = ptr[node], p1 = ptr[node + 1];
    const int deg = p1 - p0;
    const uint* xrU = (const uint*)xr2;

    float ax = 0.f, ay = 0.f;
    if (deg == 16) {
        const int gv = (idx[p0 + (lane & 15)] << 3) | etype[p0 + (lane & 15)];
        const int g0  = __builtin_amdgcn_readlane(gv, 0);
        const int g1  = __builtin_amdgcn_readlane(gv, 1);
        const int g2  = __builtin_amdgcn_readlane(gv, 2);
        const int g3  = __builtin_amdgcn_readlane(gv, 3);
        const int g4  = __builtin_amdgcn_readlane(gv, 4);
        const int g5  = __builtin_amdgcn_readlane(gv, 5);
        const int g6  = __builtin_amdgcn_readlane(gv, 6);
        const int g7  = __builtin_amdgcn_readlane(gv, 7);
        const int g8  = __builtin_amdgcn_readlane(gv, 8);
        const int g9  = __builtin_amdgcn_readlane(gv, 9);
        const int g10 = __builtin_amdgcn_readlane(gv, 10);
        const int g11 = __builtin_amdgcn_readlane(gv, 11);
        const int g12 = __builtin_amdgcn_readlane(gv, 12);
        const int g13 = __builtin_amdgcn_readlane(gv, 13);
        const int g14 = __builtin_amdgcn_readlane(gv, 14);
        const int g15 = __builtin_amdgcn_readlane(gv, 15);
        if (lane < 20) {
            GADD2(b0,  g0)  GADD2(b1,  g1)  GADD2(b2,  g2)  GADD2(b3,  g3)
            GADD2(b4,  g4)  GADD2(b5,  g5)  GADD2(b6,  g6)  GADD2(b7,  g7)
            GADD2(b8,  g8)  GADD2(b9,  g9)  GADD2(b10, g10) GADD2(b11, g11)
            GADD2(b12, g12) GADD2(b13, g13) GADD2(b14, g14) GADD2(b15, g15)
        }
    } else {                                   // generic fallback (never hit)
        for (int e = p0; e < p1; ++e) {
            const int src = __builtin_amdgcn_readfirstlane(idx[e]);
            const int et  = __builtin_amdgcn_readfirstlane(etype[e]);
            if (lane < 20) {
                const uint b = xrU[((size_t)src * 8 + et) * 32 + lane];
                ax += __uint_as_float(b << 16);
                ay += __uint_as_float(b & 0xffff0000u);
            }
        }
    }

    const float invd = 1.0f / (float)deg;
    ax *= invd; ay *= invd;

    float mx = (lane < 20) ? fmaxf(ax, ay) : -INFINITY;
    #pragma unroll
    for (int off = 32; off > 0; off >>= 1)
        mx = fmaxf(mx, __shfl_xor(mx, off, 64));
    float s = (lane < 20) ? (__expf(ax - mx) + __expf(ay - mx)) : 0.f;
    #pragma unroll
    for (int off = 32; off > 0; off >>= 1)
        s += __shfl_xor(s, off, 64);
    const float ls = __logf(s);
    if (lane < 20) {
        float2 o;
        o.x = ax - mx - ls;
        o.y = ay - mx - ls;
        *(float2*)&out[(size_t)node * kOut + lane * 2] = o;
    }
}

// ===========================================================================
// =================  OLD PATH (R10 fallback, proven 194 us)  ================
// ===========================================================================

__device__ __forceinline__ void pack_unit(const float* __restrict__ W,
                                          ushort* __restrict__ dst,
                                          int N, int frag, int lane)
{
    const int kt = frag & 31;
    const int nt = frag >> 5;
    const int n  = nt * 16 + (lane & 15);
    const int q  = lane >> 4;
    ushort hv[8];
    #pragma unroll
    for (int j = 0; j < 8; ++j) {
        const int k = kt * 32 + q * 8 + j;
        hv[j] = f2bf((n < N) ? W[(size_t)k * N + n] : 0.f);
    }
    const size_t o = ((size_t)frag * 64 + lane) * 8;
    *(ushort4*)&dst[o]     = make_ushort4(hv[0], hv[1], hv[2], hv[3]);
    *(ushort4*)&dst[o + 4] = make_ushort4(hv[4], hv[5], hv[6], hv[7]);
}

__global__ __launch_bounds__(256)
void prep_old(const float* __restrict__ x,  ushort* __restrict__ xb,
              const float* __restrict__ W1, ushort* __restrict__ W1hi,
              const float* __restrict__ W2, ushort* __restrict__ W2hi)
{
    const int b   = blockIdx.x;
    const int tid = threadIdx.x;
    if (b < 3125) {
        const size_t i = ((size_t)b * 256 + tid) * 8;
        const float4 v0 = *(const float4*)&x[i];
        const float4 v1 = *(const float4*)&x[i + 4];
        *(ushort4*)&xb[i]     = make_ushort4(f2bf(v0.x), f2bf(v0.y), f2bf(v0.z), f2bf(v0.w));
        *(ushort4*)&xb[i + 4] = make_ushort4(f2bf(v1.x), f2bf(v1.y), f2bf(v1.z), f2bf(v1.w));
    } else if (b < 3125 + 64) {
        pack_unit(W1, W1hi, kHid, (b - 3125) * 4 + (tid >> 6), tid & 63);
    } else {
        const int frag = (b - 3189) * 4 + (tid >> 6);
        if (frag < 96) pack_unit(W2, W2hi, kOut, frag, tid & 63);
    }
}

#define ACCUM_ET(ET, VX, VY)                                   \
    if      ((ET) == 0) { a0.x += (VX); a0.y += (VY); }        \
    else if ((ET) == 1) { a1.x += (VX); a1.y += (VY); }        \
    else if ((ET) == 2) { a2.x += (VX); a2.y += (VY); }        \
    else if ((ET) == 3) { a3.x += (VX); a3.y += (VY); }        \
    else if ((ET) == 4) { a4.x += (VX); a4.y += (VY); }        \
    else if ((ET) == 5) { a5.x += (VX); a5.y += (VY); }        \
    else if ((ET) == 6) { a6.x += (VX); a6.y += (VY); }        \
    else                { a7.x += (VX); a7.y += (VY); }

#define GATHER(BV, SRC) \
    const ushort2 BV = *(const ushort2*)&feat[(size_t)(SRC) * 128 + d2];

#define ACCUM_EDGE(J, BV) \
    { const int et = __builtin_amdgcn_readlane(ve, J); ACCUM_ET(et, bf2f(BV.x), bf2f(BV.y)) }

#define STORE_AGG(RR, AV) \
    *(ushort2*)&aggHi[n][(RR) * 128 + d2] = make_ushort2(f2bf(AV.x), f2bf(AV.y));

__device__ __forceinline__ void phaseA_bf16(const ushort* __restrict__ feat,
                                            const int* __restrict__ ptr,
                                            const int* __restrict__ idx,
                                            const int* __restrict__ etype,
                                            int base, ushort (*aggHi)[kLds])
{
    const int lane = threadIdx.x & 63;
    const int wid  = threadIdx.x >> 6;
    const int d2   = lane * 2;

    #pragma unroll
    for (int t = 0; t < 2; ++t) {
        const int n    = wid * 2 + t;
        const int node = base + n;
        const int p0   = ptr[node];
        const int deg  = ptr[node + 1] - p0;

        float2 a0 = {0.f,0.f}, a1 = {0.f,0.f}, a2 = {0.f,0.f}, a3 = {0.f,0.f};
        float2 a4 = {0.f,0.f}, a5 = {0.f,0.f}, a6 = {0.f,0.f}, a7 = {0.f,0.f};

        if (deg == 16) {
            const int vi = idx[p0 + (lane & 15)];
            const int ve = etype[p0 + (lane & 15)];
            const int s0  = __builtin_amdgcn_readlane(vi, 0);
            const int s1  = __builtin_amdgcn_readlane(vi, 1);
            const int s2  = __builtin_amdgcn_readlane(vi, 2);
            const int s3  = __builtin_amdgcn_readlane(vi, 3);
            const int s4  = __builtin_amdgcn_readlane(vi, 4);
            const int s5  = __builtin_amdgcn_readlane(vi, 5);
            const int s6  = __builtin_amdgcn_readlane(vi, 6);
            const int s7  = __builtin_amdgcn_readlane(vi, 7);
            const int s8  = __builtin_amdgcn_readlane(vi, 8);
            const int s9  = __builtin_amdgcn_readlane(vi, 9);
            const int s10 = __builtin_amdgcn_readlane(vi, 10);
            const int s11 = __builtin_amdgcn_readlane(vi, 11);
            const int s12 = __builtin_amdgcn_readlane(vi, 12);
            const int s13 = __builtin_amdgcn_readlane(vi, 13);
            const int s14 = __builtin_amdgcn_readlane(vi, 14);
            const int s15 = __builtin_amdgcn_readlane(vi, 15);
            GATHER(b0,  s0)  GATHER(b1,  s1)  GATHER(b2,  s2)  GATHER(b3,  s3)
            GATHER(b4,  s4)  GATHER(b5,  s5)  GATHER(b6,  s6)  GATHER(b7,  s7)
            GATHER(b8,  s8)  GATHER(b9,  s9)  GATHER(b10, s10) GATHER(b11, s11)
            GATHER(b12, s12) GATHER(b13, s13) GATHER(b14, s14) GATHER(b15, s15)
            ACCUM_EDGE(0,  b0)  ACCUM_EDGE(1,  b1)  ACCUM_EDGE(2,  b2)  ACCUM_EDGE(3,  b3)
            ACCUM_EDGE(4,  b4)  ACCUM_EDGE(5,  b5)  ACCUM_EDGE(6,  b6)  ACCUM_EDGE(7,  b7)
            ACCUM_EDGE(8,  b8)  ACCUM_EDGE(9,  b9)  ACCUM_EDGE(10, b10) ACCUM_EDGE(11, b11)
            ACCUM_EDGE(12, b12) ACCUM_EDGE(13, b13) ACCUM_EDGE(14, b14) ACCUM_EDGE(15, b15)
        } else {
            for (int e = p0; e < p0 + deg; ++e) {
                const int src = __builtin_amdgcn_readfirstlane(idx[e]);
                const int et  = __builtin_amdgcn_readfirstlane(etype[e]);
                const ushort2 u = *(const ushort2*)&feat[(size_t)src * 128 + d2];
                ACCUM_ET(et, bf2f(u.x), bf2f(u.y))
            }
        }
        STORE_AGG(0, a0) STORE_AGG(1, a1) STORE_AGG(2, a2) STORE_AGG(3, a3)
        STORE_AGG(4, a4) STORE_AGG(5, a5) STORE_AGG(6, a6) STORE_AGG(7, a7)
    }
}

__global__ __launch_bounds__(512, 4)
void rgcn_layer1(const ushort* __restrict__ xb,
                 const ushort* __restrict__ W1hi,
                 const float* __restrict__ gamma, const float* __restrict__ beta,
                 const float* __restrict__ mean,  const float* __restrict__ var,
                 const int* __restrict__ ptr, const int* __restrict__ idx,
                 const int* __restrict__ etype,
                 ushort* __restrict__ h1b)
{
    __shared__ ushort aggHi[kNT][kLds];
    const int tid  = threadIdx.x;
    const int base = blockIdx.x * kNT;

    phaseA_bf16(xb, ptr, idx, etype, base, aggHi);
    __syncthreads();

    const int lane = tid & 63;
    const int wid  = tid >> 6;
    const int m    = lane & 15;
    const int q    = lane >> 4;

    const bf16x8* Bh = (const bf16x8*)W1hi + (size_t)wid * 32 * 64 + lane;
    f32x4 acc = {0.f, 0.f, 0.f, 0.f};

    #pragma unroll 4
    for (int kt = 0; kt < 32; ++kt) {
        const bf16x8 ah = *(const bf16x8*)&aggHi[m][kt * 32 + q * 8];
        const bf16x8 bh = Bh[(size_t)kt * 64];
        acc = __builtin_amdgcn_mfma_f32_16x16x32_bf16(ah, bh, acc, 0, 0, 0);
    }

    const int c = wid * 16 + m;
    const float g  = gamma[c] * rsqrtf(var[c] + kBnEps);
    const float mu = mean[c];
    const float bt = beta[c];
    #pragma unroll
    for (int i = 0; i < 4; ++i) {
        const int node = base + q * 4 + i;
        const float invdeg = 1.0f / (float)(ptr[node + 1] - ptr[node]);
        float v = (acc[i] * invdeg - mu) * g + bt;
        v = fmaxf(v, 0.f);
        h1b[(size_t)node * kHid + c] = f2bf(v);
    }
}

__global__ __launch_bounds__(512, 4)
void rgcn_layer2(const ushort* __restrict__ h1b,
                 const ushort* __restrict__ W2hi,
                 const int* __restrict__ ptr, const int* __restrict__ idx,
                 const int* __restrict__ etype,
                 float* __restrict__ out)
{
    __shared__ ushort aggHi[kNT][kLds];
    __shared__ float logits[kNT][48];
    const int tid  = threadIdx.x;
    const int base = blockIdx.x * kNT;

    phaseA_bf16(h1b, ptr, idx, etype, base, aggHi);
    __syncthreads();

    const int lane = tid & 63;
    const int wid  = tid >> 6;
    const int m    = lane & 15;
    const int q    = lane >> 4;

    if (wid < 3) {
        const bf16x8* Bh = (const bf16x8*)W2hi + (size_t)wid * 32 * 64 + lane;
        f32x4 acc = {0.f, 0.f, 0.f, 0.f};
        #pragma unroll 4
        for (int kt = 0; kt < 32; ++kt) {
            const bf16x8 ah = *(const bf16x8*)&aggHi[m][kt * 32 + q * 8];
            const bf16x8 bh = Bh[(size_t)kt * 64];
            acc = __builtin_amdgcn_mfma_f32_16x16x32_bf16(ah, bh, acc, 0, 0, 0);
        }
        const int n = wid * 16 + m;
        if (n < kOut) {
            #pragma unroll
            for (int i = 0; i < 4; ++i) {
                const int node = base + q * 4 + i;
                const float invdeg = 1.0f / (float)(ptr[node + 1] - ptr[node]);
                logits[q * 4 + i][n] = acc[i] * invdeg;
            }
        }
    }
    __syncthreads();

    #pragma unroll
    for (int i = 0; i < 2; ++i) {
        const int nrow = wid * 2 + i;
        const int node = base + nrow;
        const float v = (lane < kOut) ? logits[nrow][lane] : -INFINITY;
        float mx = v;
        #pragma unroll
        for (int off = 32; off > 0; off >>= 1)
            mx = fmaxf(mx, __shfl_xor(mx, off, 64));
        float s = (lane < kOut) ? __expf(v - mx) : 0.f;
        #pragma unroll
        for (int off = 32; off > 0; off >>= 1)
            s += __shfl_xor(s, off, 64);
        if (lane < kOut)
            out[(size_t)node * kOut + lane] = v - mx - __logf(s);
    }
}

// ---------------------------------------------------------------------------
extern "C" void kernel_launch(void* const* d_in, const int* in_sizes, int n_in,
                              void* d_out, int out_size, void* d_ws, size_t ws_size,
                              hipStream_t stream)
{
    const float* x     = (const float*)d_in[0];
    const float* W1    = (const float*)d_in[1];
    const float* W2    = (const float*)d_in[2];
    const float* gamma = (const float*)d_in[3];
    const float* beta  = (const float*)d_in[4];
    const float* mean  = (const float*)d_in[5];
    const float* var   = (const float*)d_in[6];
    const int*   ptr   = (const int*)d_in[7];
    const int*   idx   = (const int*)d_in[8];
    const int*   et    = (const int*)d_in[9];
    float*       out   = (float*)d_out;

    char* ws = (char*)d_ws;
    constexpr size_t kNeedNew = 128393216;     // xb+h1b+W1p+W2p+xr

    if (ws_size >= kNeedNew) {
        // New path: transform-first + gather-sum
        ushort* xb  = (ushort*)ws;                           // 12,800,000
        ushort* h1b = (ushort*)(ws + 12800000);              // 12,800,000
        ushort* W1p = (ushort*)(ws + 25600000);              //    262,144
        ushort* W2p = (ushort*)(ws + 25862144);              //    131,072
        ushort* xr  = (ushort*)(ws + 25993216);              // 102,400,000 (xr1; xr2 aliases)

        prep_new<<<dim3(3125 + 64 + 32), dim3(256), 0, stream>>>(x, xb, W1, W1p, W2, W2p);
        xform<8, 1024><<<dim3(782), dim3(512), 0, stream>>>(xb, W1p, xr);
        agg_bn<<<dim3(6250), dim3(512), 0, stream>>>(xr, ptr, idx, et,
                                                     gamma, beta, mean, var, h1b);
        xform<4, 512><<<dim3(782), dim3(512), 0, stream>>>(h1b, W2p, xr);
        agg_sm<<<dim3(6250), dim3(512), 0, stream>>>(xr, ptr, idx, et, out);
    } else {
        // Fallback: proven R10 path
        ushort* h1b  = (ushort*)ws;                          // 12,800,000
        ushort* xb   = (ushort*)(ws + 12800000);             // 12,800,000
        ushort* W1hi = (ushort*)(ws + 25600000);             //    262,144
        ushort* W2hi = (ushort*)(ws + 25600000 + 262144);    //     98,304

        prep_old<<<dim3(3125 + 64 + 24), dim3(256), 0, stream>>>(x, xb, W1, W1hi, W2, W2hi);
        dim3 grid(kN / kNT), block(512);
        rgcn_layer1<<<grid, block, 0, stream>>>(xb, W1hi, gamma, beta, mean, var,
                                                ptr, idx, et, h1b);
        rgcn_layer2<<<grid, block, 0, stream>>>(h1b, W2hi, ptr, idx, et, out);
    }
}

// Round 12
// 200.271 us; speedup vs baseline: 1.0629x; 1.0629x over previous
//
#include <hip/hip_runtime.h>
#include <math.h>

typedef __attribute__((ext_vector_type(8))) short bf16x8;
typedef __attribute__((ext_vector_type(4))) float f32x4;
typedef __attribute__((ext_vector_type(2))) unsigned long long u64x2;

constexpr int kN   = 50000;
constexpr int kR   = 8;
constexpr int kIn  = 128;
constexpr int kHid = 128;
constexpr int kOut = 40;
constexpr int kNT  = 16;              // dst nodes per block (old path)
constexpr int kLds = 1032;            // old-path ushort row stride
constexpr float kBnEps = 1e-5f;

// bf16 RNE (prep only)
__device__ inline ushort f2bf(float x) {
    uint u = __float_as_uint(x);
    u += 0x7FFFu + ((u >> 16) & 1u);
    return (ushort)(u >> 16);
}
__device__ inline float bf2f(ushort s) { return __uint_as_float(((uint)s) << 16); }
// cheap half-up pack (accepted error class since R7)
__device__ inline ushort f2bf_c(float x) {
    return (ushort)((__float_as_uint(x) + 0x8000u) >> 16);
}

// ===========================================================================
// ======================  NEW PATH (xform + gather-sum)  ====================
// ===========================================================================

// ---------------------------------------------------------------------------
// prep_new: blocks 0..3124  : cast x fp32->bf16 (8 elems/thread)
//           blocks 3125..3188: pack W1' -> B-frags, cols n = r*128+h (N=1024)
//           blocks 3189..3220: pack W2' -> B-frags, cols n = r*64+h  (N=512,
//                              h>=40 zero-padded)
// Frag f = nt*4 + kt; lane L holds B[n=nt*16+(L&15)][k=kt*32+(L>>4)*8+j].
// ---------------------------------------------------------------------------
__global__ __launch_bounds__(256)
void prep_new(const float* __restrict__ x,  ushort* __restrict__ xb,
              const float* __restrict__ W1, ushort* __restrict__ W1p,
              const float* __restrict__ W2, ushort* __restrict__ W2p)
{
    const int b   = blockIdx.x;
    const int tid = threadIdx.x;
    if (b < 3125) {
        const size_t i = ((size_t)b * 256 + tid) * 8;
        const float4 v0 = *(const float4*)&x[i];
        const float4 v1 = *(const float4*)&x[i + 4];
        *(ushort4*)&xb[i]     = make_ushort4(f2bf(v0.x), f2bf(v0.y), f2bf(v0.z), f2bf(v0.w));
        *(ushort4*)&xb[i + 4] = make_ushort4(f2bf(v1.x), f2bf(v1.y), f2bf(v1.z), f2bf(v1.w));
        return;
    }
    const int lane = tid & 63;
    const int m = lane & 15, q = lane >> 4;
    ushort hv[8];
    if (b < 3125 + 64) {                        // W1': 256 frags
        const int f  = (b - 3125) * 4 + (tid >> 6);
        const int nt = f >> 2, kt = f & 3;
        const int n  = nt * 16 + m;             // n = r*128 + h
        const int r  = n >> 7, h = n & 127;
        #pragma unroll
        for (int j = 0; j < 8; ++j) {
            const int k = kt * 32 + q * 8 + j;  // k = input dim d
            hv[j] = f2bf(W1[(size_t)r * 16384 + (size_t)k * 128 + h]);
        }
        const size_t o = ((size_t)f * 64 + lane) * 8;
        *(ushort4*)&W1p[o]     = make_ushort4(hv[0], hv[1], hv[2], hv[3]);
        *(ushort4*)&W1p[o + 4] = make_ushort4(hv[4], hv[5], hv[6], hv[7]);
    } else {                                    // W2': 128 frags
        const int f  = (b - 3189) * 4 + (tid >> 6);
        const int nt = f >> 2, kt = f & 3;
        const int n  = nt * 16 + m;             // n = r*64 + h (pad h>=40)
        const int r  = n >> 6, h = n & 63;
        #pragma unroll
        for (int j = 0; j < 8; ++j) {
            const int k = kt * 32 + q * 8 + j;
            hv[j] = (h < kOut) ? f2bf(W2[(size_t)r * 5120 + (size_t)k * 40 + h])
                               : (ushort)0;
        }
        const size_t o = ((size_t)f * 64 + lane) * 8;
        *(ushort4*)&W2p[o]     = make_ushort4(hv[0], hv[1], hv[2], hv[3]);
        *(ushort4*)&W2p[o + 4] = make_ushort4(hv[4], hv[5], hv[6], hv[7]);
    }
}

// ---------------------------------------------------------------------------
// xform_body<NCOLS>: out[row][col] = in[row][:128] @ B'  (dense bf16 GEMM)
// 64-row M-tile per block. Per iteration ii the 8 waves cover 128 CONSECUTIVE
// cols (nt = ii*8 + wid); the 64x128 C tile is staged in LDS (132-ushort
// stride: conflict-free across quads) and written as 256-B contiguous
// row-chunks -> full cache lines, no write amplification.
// ---------------------------------------------------------------------------
#define LOADA(MT,KT) const bf16x8 af##MT##KT = \
    *(const bf16x8*)&As[MT * 16 + m][KT * 32 + q * 8];

template<int NCOLS>
__device__ __forceinline__ void xform_body(const ushort* __restrict__ in,
                                           const ushort* __restrict__ Bp,
                                           ushort* __restrict__ outp)
{
    constexpr int G = NCOLS / 128;             // column groups per block
    __shared__ ushort As[64][136];             // 17.4 KB (16B-aligned rows)
    __shared__ unsigned long long Cs64[64 * 33];  // 16.9 KB, 132-ushort rows
    ushort* Cs = (ushort*)Cs64;

    const int tid  = threadIdx.x;
    const int base = blockIdx.x * 64;

    {   // stage A: 64 rows x 128 bf16
        const int row = tid >> 3, c = tid & 7;
        const int gr  = base + row;
        bf16x8 v0 = {0,0,0,0,0,0,0,0}, v1 = {0,0,0,0,0,0,0,0};
        if (gr < kN) {
            v0 = *(const bf16x8*)&in[(size_t)gr * 128 + c * 8];
            v1 = *(const bf16x8*)&in[(size_t)gr * 128 + c * 8 + 64];
        }
        *(bf16x8*)&As[row][c * 8]      = v0;
        *(bf16x8*)&As[row][c * 8 + 64] = v1;
    }
    __syncthreads();

    const int lane = tid & 63, wid = tid >> 6;
    const int m = lane & 15, q = lane >> 4;

    LOADA(0,0) LOADA(0,1) LOADA(0,2) LOADA(0,3)
    LOADA(1,0) LOADA(1,1) LOADA(1,2) LOADA(1,3)
    LOADA(2,0) LOADA(2,1) LOADA(2,2) LOADA(2,3)
    LOADA(3,0) LOADA(3,1) LOADA(3,2) LOADA(3,3)

    const bf16x8* B8 = (const bf16x8*)Bp;
    const int srow = tid >> 3, scc = (tid & 7) * 16;  // store-phase mapping
    const int sgr  = base + srow;

    #pragma unroll 1
    for (int ii = 0; ii < G; ++ii) {
        const int nt = ii * 8 + wid;
        const bf16x8 b0 = B8[(size_t)(nt * 4 + 0) * 64 + lane];
        const bf16x8 b1 = B8[(size_t)(nt * 4 + 1) * 64 + lane];
        const bf16x8 b2 = B8[(size_t)(nt * 4 + 2) * 64 + lane];
        const bf16x8 b3 = B8[(size_t)(nt * 4 + 3) * 64 + lane];
        f32x4 c0 = {0.f,0.f,0.f,0.f}, c1 = {0.f,0.f,0.f,0.f};
        f32x4 c2 = {0.f,0.f,0.f,0.f}, c3 = {0.f,0.f,0.f,0.f};
        c0 = __builtin_amdgcn_mfma_f32_16x16x32_bf16(af00, b0, c0, 0, 0, 0);
        c1 = __builtin_amdgcn_mfma_f32_16x16x32_bf16(af10, b0, c1, 0, 0, 0);
        c2 = __builtin_amdgcn_mfma_f32_16x16x32_bf16(af20, b0, c2, 0, 0, 0);
        c3 = __builtin_amdgcn_mfma_f32_16x16x32_bf16(af30, b0, c3, 0, 0, 0);
        c0 = __builtin_amdgcn_mfma_f32_16x16x32_bf16(af01, b1, c0, 0, 0, 0);
        c1 = __builtin_amdgcn_mfma_f32_16x16x32_bf16(af11, b1, c1, 0, 0, 0);
        c2 = __builtin_amdgcn_mfma_f32_16x16x32_bf16(af21, b1, c2, 0, 0, 0);
        c3 = __builtin_amdgcn_mfma_f32_16x16x32_bf16(af31, b1, c3, 0, 0, 0);
        c0 = __builtin_amdgcn_mfma_f32_16x16x32_bf16(af02, b2, c0, 0, 0, 0);
        c1 = __builtin_amdgcn_mfma_f32_16x16x32_bf16(af12, b2, c1, 0, 0, 0);
        c2 = __builtin_amdgcn_mfma_f32_16x16x32_bf16(af22, b2, c2, 0, 0, 0);
        c3 = __builtin_amdgcn_mfma_f32_16x16x32_bf16(af32, b2, c3, 0, 0, 0);
        c0 = __builtin_amdgcn_mfma_f32_16x16x32_bf16(af03, b3, c0, 0, 0, 0);
        c1 = __builtin_amdgcn_mfma_f32_16x16x32_bf16(af13, b3, c1, 0, 0, 0);
        c2 = __builtin_amdgcn_mfma_f32_16x16x32_bf16(af23, b3, c2, 0, 0, 0);
        c3 = __builtin_amdgcn_mfma_f32_16x16x32_bf16(af33, b3, c3, 0, 0, 0);

        // stage C tile: col-within-group = wid*16 + m, row = mt*16 + q*4 + i
        #pragma unroll
        for (int i2 = 0; i2 < 4; ++i2) {
            Cs[(0 * 16 + q * 4 + i2) * 132 + wid * 16 + m] = f2bf_c(c0[i2]);
            Cs[(1 * 16 + q * 4 + i2) * 132 + wid * 16 + m] = f2bf_c(c1[i2]);
            Cs[(2 * 16 + q * 4 + i2) * 132 + wid * 16 + m] = f2bf_c(c2[i2]);
            Cs[(3 * 16 + q * 4 + i2) * 132 + wid * 16 + m] = f2bf_c(c3[i2]);
        }
        __syncthreads();
        // read back 32 B per thread (8-B aligned LDS reads)
        const unsigned long long* s =
            (const unsigned long long*)&Cs[srow * 132 + scc];
        const unsigned long long v0_ = s[0], v1_ = s[1], v2_ = s[2], v3_ = s[3];
        __syncthreads();
        // coalesced 256-B row-chunk stores (issued async; drained at next bar)
        if (sgr < kN) {
            unsigned long long* d =
                (unsigned long long*)&outp[(size_t)sgr * NCOLS + ii * 128 + scc];
            u64x2 p0; p0.x = v0_; p0.y = v1_;
            u64x2 p1; p1.x = v2_; p1.y = v3_;
            *(u64x2*)d       = p0;
            *(u64x2*)(d + 2) = p1;
        }
    }
}

__global__ __launch_bounds__(512, 4)
void xform_l1(const ushort* __restrict__ in, const ushort* __restrict__ Bp,
              ushort* __restrict__ outp)
{ xform_body<1024>(in, Bp, outp); }

__global__ __launch_bounds__(512, 4)
void xform_l2(const ushort* __restrict__ in, const ushort* __restrict__ Bp,
              ushort* __restrict__ outp)
{ xform_body<512>(in, Bp, outp); }

// ---------------------------------------------------------------------------
// agg_bn: h1[n][c] = relu(bn( (sum_e xr1[(src_e*8+et_e)]) / deg ))
// TWO nodes per wave (32 contiguous edges, one metadata load, 32 gathers in
// flight). Lane owns channel pair 2L, 2L+1. No LDS, no barrier, no branches.
// ---------------------------------------------------------------------------
#define RLG(J)  const int g##J = __builtin_amdgcn_readlane(gv, J);
#define LDU(B, J) const uint B = xrU[(size_t)g##J * 64 + lane];
#define ACC2(AX, AY, B) { AX += __uint_as_float((B) << 16); \
                          AY += __uint_as_float((B) & 0xffff0000u); }

__global__ __launch_bounds__(512, 4)
void agg_bn(const ushort* __restrict__ xr1,
            const int* __restrict__ ptr, const int* __restrict__ idx,
            const int* __restrict__ etype,
            const float* __restrict__ gamma, const float* __restrict__ beta,
            const float* __restrict__ mean,  const float* __restrict__ var,
            ushort* __restrict__ h1b)
{
    const int lane = threadIdx.x & 63;
    const int wid  = threadIdx.x >> 6;
    const int nA   = blockIdx.x * 16 + wid * 2;
    const int p0 = ptr[nA], p1 = ptr[nA + 1], p2 = ptr[nA + 2];
    const int degA = p1 - p0, degB = p2 - p1;
    const uint* xrU = (const uint*)xr1;

    float axA = 0.f, ayA = 0.f, axB = 0.f, ayB = 0.f;
    if (degA == 16 && degB == 16) {
        const int gv = (idx[p0 + (lane & 31)] << 3) | etype[p0 + (lane & 31)];
        RLG(0)  RLG(1)  RLG(2)  RLG(3)  RLG(4)  RLG(5)  RLG(6)  RLG(7)
        RLG(8)  RLG(9)  RLG(10) RLG(11) RLG(12) RLG(13) RLG(14) RLG(15)
        RLG(16) RLG(17) RLG(18) RLG(19) RLG(20) RLG(21) RLG(22) RLG(23)
        RLG(24) RLG(25) RLG(26) RLG(27) RLG(28) RLG(29) RLG(30) RLG(31)
        LDU(bA0,  0)  LDU(bA1,  1)  LDU(bA2,  2)  LDU(bA3,  3)
        LDU(bA4,  4)  LDU(bA5,  5)  LDU(bA6,  6)  LDU(bA7,  7)
        LDU(bA8,  8)  LDU(bA9,  9)  LDU(bA10, 10) LDU(bA11, 11)
        LDU(bA12, 12) LDU(bA13, 13) LDU(bA14, 14) LDU(bA15, 15)
        LDU(bB0,  16) LDU(bB1,  17) LDU(bB2,  18) LDU(bB3,  19)
        LDU(bB4,  20) LDU(bB5,  21) LDU(bB6,  22) LDU(bB7,  23)
        LDU(bB8,  24) LDU(bB9,  25) LDU(bB10, 26) LDU(bB11, 27)
        LDU(bB12, 28) LDU(bB13, 29) LDU(bB14, 30) LDU(bB15, 31)
        ACC2(axA, ayA, bA0)  ACC2(axA, ayA, bA1)  ACC2(axA, ayA, bA2)
        ACC2(axA, ayA, bA3)  ACC2(axA, ayA, bA4)  ACC2(axA, ayA, bA5)
        ACC2(axA, ayA, bA6)  ACC2(axA, ayA, bA7)  ACC2(axA, ayA, bA8)
        ACC2(axA, ayA, bA9)  ACC2(axA, ayA, bA10) ACC2(axA, ayA, bA11)
        ACC2(axA, ayA, bA12) ACC2(axA, ayA, bA13) ACC2(axA, ayA, bA14)
        ACC2(axA, ayA, bA15)
        ACC2(axB, ayB, bB0)  ACC2(axB, ayB, bB1)  ACC2(axB, ayB, bB2)
        ACC2(axB, ayB, bB3)  ACC2(axB, ayB, bB4)  ACC2(axB, ayB, bB5)
        ACC2(axB, ayB, bB6)  ACC2(axB, ayB, bB7)  ACC2(axB, ayB, bB8)
        ACC2(axB, ayB, bB9)  ACC2(axB, ayB, bB10) ACC2(axB, ayB, bB11)
        ACC2(axB, ayB, bB12) ACC2(axB, ayB, bB13) ACC2(axB, ayB, bB14)
        ACC2(axB, ayB, bB15)
    } else {                                   // generic fallback (never hit)
        for (int e = p0; e < p1; ++e) {
            const int src = __builtin_amdgcn_readfirstlane(idx[e]);
            const int et  = __builtin_amdgcn_readfirstlane(etype[e]);
            const uint b  = xrU[((size_t)src * 8 + et) * 64 + lane];
            ACC2(axA, ayA, b)
        }
        for (int e = p1; e < p2; ++e) {
            const int src = __builtin_amdgcn_readfirstlane(idx[e]);
            const int et  = __builtin_amdgcn_readfirstlane(etype[e]);
            const uint b  = xrU[((size_t)src * 8 + et) * 64 + lane];
            ACC2(axB, ayB, b)
        }
    }

    const int c0 = lane * 2;
    const float2 gm = *(const float2*)&gamma[c0];
    const float2 bt = *(const float2*)&beta[c0];
    const float2 mu = *(const float2*)&mean[c0];
    const float2 vr = *(const float2*)&var[c0];
    const float gx = gm.x * rsqrtf(vr.x + kBnEps);
    const float gy = gm.y * rsqrtf(vr.y + kBnEps);
    const float iA = 1.0f / (float)degA;
    const float iB = 1.0f / (float)degB;

    float v0 = fmaxf((axA * iA - mu.x) * gx + bt.x, 0.f);
    float v1 = fmaxf((ayA * iA - mu.y) * gy + bt.y, 0.f);
    uint px = (__float_as_uint(v0) + 0x8000u) >> 16;
    uint py = (__float_as_uint(v1) + 0x8000u) & 0xffff0000u;
    ((uint*)h1b)[(size_t)nA * 64 + lane] = px | py;

    v0 = fmaxf((axB * iB - mu.x) * gx + bt.x, 0.f);
    v1 = fmaxf((ayB * iB - mu.y) * gy + bt.y, 0.f);
    px = (__float_as_uint(v0) + 0x8000u) >> 16;
    py = (__float_as_uint(v1) + 0x8000u) & 0xffff0000u;
    ((uint*)h1b)[(size_t)(nA + 1) * 64 + lane] = px | py;
}

// ---------------------------------------------------------------------------
// agg_sm: out[n][:40] = log_softmax( (sum_e xr2[src_e*8+et_e]) / deg )
// One wave per node; lanes 0..19 own logit pairs 2L, 2L+1.
// ---------------------------------------------------------------------------
#define GADD2(BV, GJ) \
    const uint BV = xrU[(size_t)(GJ) * 32 + lane]; \
    ax += __uint_as_float((BV) << 16); \
    ay += __uint_as_float((BV) & 0xffff0000u);

__global__ __launch_bounds__(512, 4)
void agg_sm(const ushort* __restrict__ xr2,
            const int* __restrict__ ptr, const int* __restrict__ idx,
            const int* __restrict__ etype,
            float* __restrict__ out)
{
    const int lane = threadIdx.x & 63;
    const int wid  = threadIdx.x >> 6;
    const int node = blockIdx.x * 8 + wid;
    const int p0 = ptr[node], p1 = ptr[node + 1];
    const int deg = p1 - p0;
    const uint* xrU = (const uint*)xr2;

    float ax = 0.f, ay = 0.f;
    if (deg == 16) {
        const int gv = (idx[p0 + (lane & 15)] << 3) | etype[p0 + (lane & 15)];
        const int g0  = __builtin_amdgcn_readlane(gv, 0);
        const int g1  = __builtin_amdgcn_readlane(gv, 1);
        const int g2  = __builtin_amdgcn_readlane(gv, 2);
        const int g3  = __builtin_amdgcn_readlane(gv, 3);
        const int g4  = __builtin_amdgcn_readlane(gv, 4);
        const int g5  = __builtin_amdgcn_readlane(gv, 5);
        const int g6  = __builtin_amdgcn_readlane(gv, 6);
        const int g7  = __builtin_amdgcn_readlane(gv, 7);
        const int g8  = __builtin_amdgcn_readlane(gv, 8);
        const int g9  = __builtin_amdgcn_readlane(gv, 9);
        const int g10 = __builtin_amdgcn_readlane(gv, 10);
        const int g11 = __builtin_amdgcn_readlane(gv, 11);
        const int g12 = __builtin_amdgcn_readlane(gv, 12);
        const int g13 = __builtin_amdgcn_readlane(gv, 13);
        const int g14 = __builtin_amdgcn_readlane(gv, 14);
        const int g15 = __builtin_amdgcn_readlane(gv, 15);
        if (lane < 20) {
            GADD2(b0,  g0)  GADD2(b1,  g1)  GADD2(b2,  g2)  GADD2(b3,  g3)
            GADD2(b4,  g4)  GADD2(b5,  g5)  GADD2(b6,  g6)  GADD2(b7,  g7)
            GADD2(b8,  g8)  GADD2(b9,  g9)  GADD2(b10, g10) GADD2(b11, g11)
            GADD2(b12, g12) GADD2(b13, g13) GADD2(b14, g14) GADD2(b15, g15)
        }
    } else {                                   // generic fallback (never hit)
        for (int e = p0; e < p1; ++e) {
            const int src = __builtin_amdgcn_readfirstlane(idx[e]);
            const int et  = __builtin_amdgcn_readfirstlane(etype[e]);
            if (lane < 20) {
                const uint b = xrU[((size_t)src * 8 + et) * 32 + lane];
                ax += __uint_as_float(b << 16);
                ay += __uint_as_float(b & 0xffff0000u);
            }
        }
    }

    const float invd = 1.0f / (float)deg;
    ax *= invd; ay *= invd;

    float mx = (lane < 20) ? fmaxf(ax, ay) : -INFINITY;
    #pragma unroll
    for (int off = 32; off > 0; off >>= 1)
        mx = fmaxf(mx, __shfl_xor(mx, off, 64));
    float s = (lane < 20) ? (__expf(ax - mx) + __expf(ay - mx)) : 0.f;
    #pragma unroll
    for (int off = 32; off > 0; off >>= 1)
        s += __shfl_xor(s, off, 64);
    const float ls = __logf(s);
    if (lane < 20) {
        float2 o;
        o.x = ax - mx - ls;
        o.y = ay - mx - ls;
        *(float2*)&out[(size_t)node * kOut + lane * 2] = o;
    }
}

// ===========================================================================
// =================  OLD PATH (R10 fallback, proven 194 us)  ================
// ===========================================================================

__device__ __forceinline__ void pack_unit(const float* __restrict__ W,
                                          ushort* __restrict__ dst,
                                          int N, int frag, int lane)
{
    const int kt = frag & 31;
    const int nt = frag >> 5;
    const int n  = nt * 16 + (lane & 15);
    const int q  = lane >> 4;
    ushort hv[8];
    #pragma unroll
    for (int j = 0; j < 8; ++j) {
        const int k = kt * 32 + q * 8 + j;
        hv[j] = f2bf((n < N) ? W[(size_t)k * N + n] : 0.f);
    }
    const size_t o = ((size_t)frag * 64 + lane) * 8;
    *(ushort4*)&dst[o]     = make_ushort4(hv[0], hv[1], hv[2], hv[3]);
    *(ushort4*)&dst[o + 4] = make_ushort4(hv[4], hv[5], hv[6], hv[7]);
}

__global__ __launch_bounds__(256)
void prep_old(const float* __restrict__ x,  ushort* __restrict__ xb,
              const float* __restrict__ W1, ushort* __restrict__ W1hi,
              const float* __restrict__ W2, ushort* __restrict__ W2hi)
{
    const int b   = blockIdx.x;
    const int tid = threadIdx.x;
    if (b < 3125) {
        const size_t i = ((size_t)b * 256 + tid) * 8;
        const float4 v0 = *(const float4*)&x[i];
        const float4 v1 = *(const float4*)&x[i + 4];
        *(ushort4*)&xb[i]     = make_ushort4(f2bf(v0.x), f2bf(v0.y), f2bf(v0.z), f2bf(v0.w));
        *(ushort4*)&xb[i + 4] = make_ushort4(f2bf(v1.x), f2bf(v1.y), f2bf(v1.z), f2bf(v1.w));
    } else if (b < 3125 + 64) {
        pack_unit(W1, W1hi, kHid, (b - 3125) * 4 + (tid >> 6), tid & 63);
    } else {
        const int frag = (b - 3189) * 4 + (tid >> 6);
        if (frag < 96) pack_unit(W2, W2hi, kOut, frag, tid & 63);
    }
}

#define ACCUM_ET(ET, VX, VY)                                   \
    if      ((ET) == 0) { a0.x += (VX); a0.y += (VY); }        \
    else if ((ET) == 1) { a1.x += (VX); a1.y += (VY); }        \
    else if ((ET) == 2) { a2.x += (VX); a2.y += (VY); }        \
    else if ((ET) == 3) { a3.x += (VX); a3.y += (VY); }        \
    else if ((ET) == 4) { a4.x += (VX); a4.y += (VY); }        \
    else if ((ET) == 5) { a5.x += (VX); a5.y += (VY); }        \
    else if ((ET) == 6) { a6.x += (VX); a6.y += (VY); }        \
    else                { a7.x += (VX); a7.y += (VY); }

#define GATHER(BV, SRC) \
    const ushort2 BV = *(const ushort2*)&feat[(size_t)(SRC) * 128 + d2];

#define ACCUM_EDGE(J, BV) \
    { const int et = __builtin_amdgcn_readlane(ve, J); ACCUM_ET(et, bf2f(BV.x), bf2f(BV.y)) }

#define STORE_AGG(RR, AV) \
    *(ushort2*)&aggHi[n][(RR) * 128 + d2] = make_ushort2(f2bf(AV.x), f2bf(AV.y));

__device__ __forceinline__ void phaseA_bf16(const ushort* __restrict__ feat,
                                            const int* __restrict__ ptr,
                                            const int* __restrict__ idx,
                                            const int* __restrict__ etype,
                                            int base, ushort (*aggHi)[kLds])
{
    const int lane = threadIdx.x & 63;
    const int wid  = threadIdx.x >> 6;
    const int d2   = lane * 2;

    #pragma unroll
    for (int t = 0; t < 2; ++t) {
        const int n    = wid * 2 + t;
        const int node = base + n;
        const int p0   = ptr[node];
        const int deg  = ptr[node + 1] - p0;

        float2 a0 = {0.f,0.f}, a1 = {0.f,0.f}, a2 = {0.f,0.f}, a3 = {0.f,0.f};
        float2 a4 = {0.f,0.f}, a5 = {0.f,0.f}, a6 = {0.f,0.f}, a7 = {0.f,0.f};

        if (deg == 16) {
            const int vi = idx[p0 + (lane & 15)];
            const int ve = etype[p0 + (lane & 15)];
            const int s0  = __builtin_amdgcn_readlane(vi, 0);
            const int s1  = __builtin_amdgcn_readlane(vi, 1);
            const int s2  = __builtin_amdgcn_readlane(vi, 2);
            const int s3  = __builtin_amdgcn_readlane(vi, 3);
            const int s4  = __builtin_amdgcn_readlane(vi, 4);
            const int s5  = __builtin_amdgcn_readlane(vi, 5);
            const int s6  = __builtin_amdgcn_readlane(vi, 6);
            const int s7  = __builtin_amdgcn_readlane(vi, 7);
            const int s8  = __builtin_amdgcn_readlane(vi, 8);
            const int s9  = __builtin_amdgcn_readlane(vi, 9);
            const int s10 = __builtin_amdgcn_readlane(vi, 10);
            const int s11 = __builtin_amdgcn_readlane(vi, 11);
            const int s12 = __builtin_amdgcn_readlane(vi, 12);
            const int s13 = __builtin_amdgcn_readlane(vi, 13);
            const int s14 = __builtin_amdgcn_readlane(vi, 14);
            const int s15 = __builtin_amdgcn_readlane(vi, 15);
            GATHER(b0,  s0)  GATHER(b1,  s1)  GATHER(b2,  s2)  GATHER(b3,  s3)
            GATHER(b4,  s4)  GATHER(b5,  s5)  GATHER(b6,  s6)  GATHER(b7,  s7)
            GATHER(b8,  s8)  GATHER(b9,  s9)  GATHER(b10, s10) GATHER(b11, s11)
            GATHER(b12, s12) GATHER(b13, s13) GATHER(b14, s14) GATHER(b15, s15)
            ACCUM_EDGE(0,  b0)  ACCUM_EDGE(1,  b1)  ACCUM_EDGE(2,  b2)  ACCUM_EDGE(3,  b3)
            ACCUM_EDGE(4,  b4)  ACCUM_EDGE(5,  b5)  ACCUM_EDGE(6,  b6)  ACCUM_EDGE(7,  b7)
            ACCUM_EDGE(8,  b8)  ACCUM_EDGE(9,  b9)  ACCUM_EDGE(10, b10) ACCUM_EDGE(11, b11)
            ACCUM_EDGE(12, b12) ACCUM_EDGE(13, b13) ACCUM_EDGE(14, b14) ACCUM_EDGE(15, b15)
        } else {
            for (int e = p0; e < p0 + deg; ++e) {
                const int src = __builtin_amdgcn_readfirstlane(idx[e]);
                const int et  = __builtin_amdgcn_readfirstlane(etype[e]);
                const ushort2 u = *(const ushort2*)&feat[(size_t)src * 128 + d2];
                ACCUM_ET(et, bf2f(u.x), bf2f(u.y))
            }
        }
        STORE_AGG(0, a0) STORE_AGG(1, a1) STORE_AGG(2, a2) STORE_AGG(3, a3)
        STORE_AGG(4, a4) STORE_AGG(5, a5) STORE_AGG(6, a6) STORE_AGG(7, a7)
    }
}

__global__ __launch_bounds__(512, 4)
void rgcn_layer1(const ushort* __restrict__ xb,
                 const ushort* __restrict__ W1hi,
                 const float* __restrict__ gamma, const float* __restrict__ beta,
                 const float* __restrict__ mean,  const float* __restrict__ var,
                 const int* __restrict__ ptr, const int* __restrict__ idx,
                 const int* __restrict__ etype,
                 ushort* __restrict__ h1b)
{
    __shared__ ushort aggHi[kNT][kLds];
    const int tid  = threadIdx.x;
    const int base = blockIdx.x * kNT;

    phaseA_bf16(xb, ptr, idx, etype, base, aggHi);
    __syncthreads();

    const int lane = tid & 63;
    const int wid  = tid >> 6;
    const int m    = lane & 15;
    const int q    = lane >> 4;

    const bf16x8* Bh = (const bf16x8*)W1hi + (size_t)wid * 32 * 64 + lane;
    f32x4 acc = {0.f, 0.f, 0.f, 0.f};

    #pragma unroll 4
    for (int kt = 0; kt < 32; ++kt) {
        const bf16x8 ah = *(const bf16x8*)&aggHi[m][kt * 32 + q * 8];
        const bf16x8 bh = Bh[(size_t)kt * 64];
        acc = __builtin_amdgcn_mfma_f32_16x16x32_bf16(ah, bh, acc, 0, 0, 0);
    }

    const int c = wid * 16 + m;
    const float g  = gamma[c] * rsqrtf(var[c] + kBnEps);
    const float mu = mean[c];
    const float bt = beta[c];
    #pragma unroll
    for (int i = 0; i < 4; ++i) {
        const int node = base + q * 4 + i;
        const float invdeg = 1.0f / (float)(ptr[node + 1] - ptr[node]);
        float v = (acc[i] * invdeg - mu) * g + bt;
        v = fmaxf(v, 0.f);
        h1b[(size_t)node * kHid + c] = f2bf(v);
    }
}

__global__ __launch_bounds__(512, 4)
void rgcn_layer2(const ushort* __restrict__ h1b,
                 const ushort* __restrict__ W2hi,
                 const int* __restrict__ ptr, const int* __restrict__ idx,
                 const int* __restrict__ etype,
                 float* __restrict__ out)
{
    __shared__ ushort aggHi[kNT][kLds];
    __shared__ float logits[kNT][48];
    const int tid  = threadIdx.x;
    const int base = blockIdx.x * kNT;

    phaseA_bf16(h1b, ptr, idx, etype, base, aggHi);
    __syncthreads();

    const int lane = tid & 63;
    const int wid  = tid >> 6;
    const int m    = lane & 15;
    const int q    = lane >> 4;

    if (wid < 3) {
        const bf16x8* Bh = (const bf16x8*)W2hi + (size_t)wid * 32 * 64 + lane;
        f32x4 acc = {0.f, 0.f, 0.f, 0.f};
        #pragma unroll 4
        for (int kt = 0; kt < 32; ++kt) {
            const bf16x8 ah = *(const bf16x8*)&aggHi[m][kt * 32 + q * 8];
            const bf16x8 bh = Bh[(size_t)kt * 64];
            acc = __builtin_amdgcn_mfma_f32_16x16x32_bf16(ah, bh, acc, 0, 0, 0);
        }
        const int n = wid * 16 + m;
        if (n < kOut) {
            #pragma unroll
            for (int i = 0; i < 4; ++i) {
                const int node = base + q * 4 + i;
                const float invdeg = 1.0f / (float)(ptr[node + 1] - ptr[node]);
                logits[q * 4 + i][n] = acc[i] * invdeg;
            }
        }
    }
    __syncthreads();

    #pragma unroll
    for (int i = 0; i < 2; ++i) {
        const int nrow = wid * 2 + i;
        const int node = base + nrow;
        const float v = (lane < kOut) ? logits[nrow][lane] : -INFINITY;
        float mx = v;
        #pragma unroll
        for (int off = 32; off > 0; off >>= 1)
            mx = fmaxf(mx, __shfl_xor(mx, off, 64));
        float s = (lane < kOut) ? __expf(v - mx) : 0.f;
        #pragma unroll
        for (int off = 32; off > 0; off >>= 1)
            s += __shfl_xor(s, off, 64);
        if (lane < kOut)
            out[(size_t)node * kOut + lane] = v - mx - __logf(s);
    }
}

// ---------------------------------------------------------------------------
extern "C" void kernel_launch(void* const* d_in, const int* in_sizes, int n_in,
                              void* d_out, int out_size, void* d_ws, size_t ws_size,
                              hipStream_t stream)
{
    const float* x     = (const float*)d_in[0];
    const float* W1    = (const float*)d_in[1];
    const float* W2    = (const float*)d_in[2];
    const float* gamma = (const float*)d_in[3];
    const float* beta  = (const float*)d_in[4];
    const float* mean  = (const float*)d_in[5];
    const float* var   = (const float*)d_in[6];
    const int*   ptr   = (const int*)d_in[7];
    const int*   idx   = (const int*)d_in[8];
    const int*   et    = (const int*)d_in[9];
    float*       out   = (float*)d_out;

    char* ws = (char*)d_ws;
    constexpr size_t kNeedNew = 128393216;     // xb+h1b+W1p+W2p+xr

    if (ws_size >= kNeedNew) {
        // New path: transform-first + gather-sum
        ushort* xb  = (ushort*)ws;                           // 12,800,000
        ushort* h1b = (ushort*)(ws + 12800000);              // 12,800,000
        ushort* W1p = (ushort*)(ws + 25600000);              //    262,144
        ushort* W2p = (ushort*)(ws + 25862144);              //    131,072
        ushort* xr  = (ushort*)(ws + 25993216);              // 102,400,000 (xr1; xr2 aliases)

        prep_new<<<dim3(3125 + 64 + 32), dim3(256), 0, stream>>>(x, xb, W1, W1p, W2, W2p);
        xform_l1<<<dim3(782), dim3(512), 0, stream>>>(xb, W1p, xr);
        agg_bn<<<dim3(3125), dim3(512), 0, stream>>>(xr, ptr, idx, et,
                                                     gamma, beta, mean, var, h1b);
        xform_l2<<<dim3(782), dim3(512), 0, stream>>>(h1b, W2p, xr);
        agg_sm<<<dim3(6250), dim3(512), 0, stream>>>(xr, ptr, idx, et, out);
    } else {
        // Fallback: proven R10 path
        ushort* h1b  = (ushort*)ws;                          // 12,800,000
        ushort* xb   = (ushort*)(ws + 12800000);             // 12,800,000
        ushort* W1hi = (ushort*)(ws + 25600000);             //    262,144
        ushort* W2hi = (ushort*)(ws + 25600000 + 262144);    //     98,304

        prep_old<<<dim3(3125 + 64 + 24), dim3(256), 0, stream>>>(x, xb, W1, W1hi, W2, W2hi);
        dim3 grid(kN / kNT), block(512);
        rgcn_layer1<<<grid, block, 0, stream>>>(xb, W1hi, gamma, beta, mean, var,
                                                ptr, idx, et, h1b);
        rgcn_layer2<<<grid, block, 0, stream>>>(h1b, W2hi, ptr, idx, et, out);
    }
}